// Round 6
// baseline (17090.216 us; speedup 1.0000x reference)
//
#include <hip/hip_runtime.h>

#define T_ 256
#define B_ 128
#define I_ 1024
#define H_ 1024
#define G_ 4096   // 4*H
#define BH (B_*H_)   // 131072
#define TB (T_*B_)   // 32768

typedef float f32x4 __attribute__((ext_vector_type(4)));
typedef short bf16x8 __attribute__((ext_vector_type(8)));

__device__ inline unsigned short f2bf(float f) {
    union { float f; unsigned int u; } v; v.f = f;
    unsigned int u = v.u;
    unsigned int r = (u + 0x7fffu + ((u >> 16) & 1u)) >> 16;
    return (unsigned short)r;
}
__device__ inline float bf2f(unsigned short s) {
    union { unsigned int u; float f; } v; v.u = ((unsigned int)s) << 16;
    return v.f;
}
__device__ inline float sigmoidf_(float x) { return 1.0f / (1.0f + __expf(-x)); }
__device__ inline float tanhf_(float x) {
    x = fminf(15.0f, fmaxf(-15.0f, x));
    float e = __expf(2.0f * x);
    return (e - 1.0f) / (e + 1.0f);
}

// ---------------- convert fp32 -> bf16 (vectorized) ----------------
__global__ void cvt_kernel(const float* __restrict__ src, unsigned short* __restrict__ dst, int n) {
    int i = (blockIdx.x * blockDim.x + threadIdx.x) * 4;
    int stride = gridDim.x * blockDim.x * 4;
    for (; i < n; i += stride) {
        float4 v = *reinterpret_cast<const float4*>(src + i);
        ushort4 o;
        o.x = f2bf(v.x); o.y = f2bf(v.y); o.z = f2bf(v.z); o.w = f2bf(v.w);
        *reinterpret_cast<ushort4*>(dst + i) = o;
    }
}

__global__ void bias_kernel(const float* __restrict__ a, const float* __restrict__ b, float* __restrict__ out) {
    int i = blockIdx.x * blockDim.x + threadIdx.x;
    if (i < G_) out[i] = a[i] + b[i];
}

// ---------------- pre-GEMM: gates_x = x @ Wih^T + bias  (bf16 out) ----------------
__global__ __launch_bounds__(256) void pregemm(
    const unsigned short* __restrict__ xb,   // [32768][1024] bf16
    const unsigned short* __restrict__ wih,  // [4096][1024] bf16
    const float* __restrict__ bias,          // [4096]
    unsigned short* __restrict__ gx)         // [32768][4096] bf16
{
    int wgid = (blockIdx.x & 7) * 1024 + (blockIdx.x >> 3);
    int mg = wgid & 255;
    int ng = wgid >> 8;
    int m0 = mg * 128, n0 = ng * 128;
    int tid = threadIdx.x;
    int w = tid >> 6, l = tid & 63;
    int qm = (w >> 1) * 64, qn = (w & 1) * 64;
    int lr = l & 15, lk = (l >> 4) * 8, lq = l >> 4;

    const unsigned short* ap = xb  + (size_t)(m0 + qm + lr) * I_ + lk;
    const unsigned short* bp = wih + (size_t)(n0 + qn + lr) * I_ + lk;

    f32x4 acc[4][4] = {};
    #pragma unroll 4
    for (int kk = 0; kk < 32; ++kk) {
        bf16x8 a[4], b[4];
        #pragma unroll
        for (int mt = 0; mt < 4; ++mt)
            a[mt] = *reinterpret_cast<const bf16x8*>(ap + (size_t)mt * 16 * I_ + kk * 32);
        #pragma unroll
        for (int nt = 0; nt < 4; ++nt)
            b[nt] = *reinterpret_cast<const bf16x8*>(bp + (size_t)nt * 16 * I_ + kk * 32);
        #pragma unroll
        for (int mt = 0; mt < 4; ++mt)
            #pragma unroll
            for (int nt = 0; nt < 4; ++nt)
                acc[mt][nt] = __builtin_amdgcn_mfma_f32_16x16x32_bf16(a[mt], b[nt], acc[mt][nt], 0, 0, 0);
    }
    #pragma unroll
    for (int mt = 0; mt < 4; ++mt) {
        #pragma unroll
        for (int nt = 0; nt < 4; ++nt) {
            #pragma unroll
            for (int r = 0; r < 4; ++r) {
                int m = m0 + qm + mt * 16 + lq * 4 + r;
                int n = n0 + qn + nt * 16 + lr;
                gx[(size_t)m * G_ + n] = f2bf(acc[mt][nt][r] + bias[n]);
            }
        }
    }
}

// ---------------- persistent 4-stream recurrent kernel ----------------
// 64 blocks x 512 threads; block ng owns cols 16*ng..+15 for ALL batch rows.
// 4 independent batch-streams (rows 32s..32s+31) share the Whh LDS slice and
// are processed round-robin; per-stream split-phase barriers (arrive early,
// wait one full iteration later) hide the grid-sync latency.
__global__ __launch_bounds__(512, 2) void lstm_recur4(
    const unsigned short* __restrict__ whh,   // [4096][1024] bf16
    const unsigned short* __restrict__ gx,    // [32768][4096] bf16
    const float* __restrict__ c0,             // [128][1024]
    unsigned short* __restrict__ hbuf,        // [2][128][1024] bf16 (buf 0 = h0)
    float* __restrict__ ys,                   // [256][128][1024]
    float* __restrict__ hT, float* __restrict__ cT,
    unsigned* __restrict__ bar)               // 4 streams x 512 words
{
    __shared__ unsigned short whh_lds[8192 * 8];   // 128 KB: [ck][row][8]
    __shared__ float lds_g[4][32][16];             // 8 KB gate accumulators

    const int bid = blockIdx.x;               // 0..63 = col group
    const int n0 = bid * 16;
    const int tid = threadIdx.x;
    const int w = tid >> 6, l = tid & 63;
    const int mh = w >> 2, kq = w & 3;        // wave roles: m-half, k-quarter
    const int lr = l & 15, lkidx = l >> 4;

    // ---- stage Whh slice into LDS once (k-major, round-5-verified) ----
    for (int it = 0; it < 16; ++it) {
        int idx = it * 512 + tid;
        int row = idx >> 7;
        int ck  = idx & 127;
        int gg = row >> 4, cc = row & 15;
        bf16x8 v = *reinterpret_cast<const bf16x8*>(
            whh + (size_t)(gg * 1024 + n0 + cc) * H_ + ck * 8);
        *reinterpret_cast<bf16x8*>(whh_lds + ((size_t)ck * 64 + row) * 8) = v;
    }
    __syncthreads();

    const unsigned short* bwave = whh_lds + (((size_t)(kq * 32 + lkidx)) * 64 + lr) * 8;

    const int erow = tid >> 4, ecol = tid & 15;

    // per-stream persistent state
    float c[4];
    unsigned short gxr[4][4];
    #pragma unroll
    for (int s = 0; s < 4; ++s) {
        size_t eo = (size_t)(s * 32 + erow) * H_ + n0 + ecol;
        c[s] = c0[eo];
        const unsigned short* p = gx + (size_t)(s * 32 + erow) * G_ + n0 + ecol;
        gxr[s][0] = p[0]; gxr[s][1] = p[1024]; gxr[s][2] = p[2048]; gxr[s][3] = p[3072];
    }

    unsigned long long hqA[16], hqB[16];

    // batched agent-scope h loads for (parity, stream)
#define LOAD_H(PAR, S, HQ)                                                          \
    {                                                                               \
        const unsigned long long* hp64 = (const unsigned long long*)(               \
            hbuf + (size_t)(PAR) * BH + (size_t)((S) * 32 + mh * 16 + lr) * H_      \
            + kq * 256) + lkidx * 2;                                                \
        _Pragma("unroll")                                                           \
        for (int kk = 0; kk < 8; ++kk) {                                            \
            HQ[2*kk]   = __hip_atomic_load(hp64 + kk * 8,                           \
                             __ATOMIC_RELAXED, __HIP_MEMORY_SCOPE_AGENT);           \
            HQ[2*kk+1] = __hip_atomic_load(hp64 + kk * 8 + 1,                       \
                             __ATOMIC_RELAXED, __HIP_MEMORY_SCOPE_AGENT);           \
        }                                                                           \
    }

#define ARRIVE(S, STEP)                                                             \
    if (tid == 0) {                                                                 \
        unsigned* gb = bar + (S) * 512;                                             \
        unsigned tgt = (unsigned)((STEP) * 8 + 7);                                  \
        unsigned old = __hip_atomic_fetch_add(gb + (bid & 7) * 32, 1u,              \
                           __ATOMIC_RELAXED, __HIP_MEMORY_SCOPE_AGENT);             \
        if (old == tgt) {                                                           \
            unsigned mold = __hip_atomic_fetch_add(gb + 256, 1u,                    \
                               __ATOMIC_RELAXED, __HIP_MEMORY_SCOPE_AGENT);         \
            if (mold == tgt)                                                        \
                __hip_atomic_store(gb + 288, (unsigned)((STEP) + 1),                \
                                   __ATOMIC_RELAXED, __HIP_MEMORY_SCOPE_AGENT);     \
        }                                                                           \
    }

#define WAIT(S, STEP)                                                               \
    {                                                                               \
        if (tid == 0) {                                                             \
            const unsigned* gen = bar + (S) * 512 + 288;                            \
            while (__hip_atomic_load(gen, __ATOMIC_RELAXED,                         \
                                     __HIP_MEMORY_SCOPE_AGENT)                      \
                   < (unsigned)((STEP) + 1))                                        \
                __builtin_amdgcn_s_sleep(1);                                        \
        }                                                                           \
        __syncthreads();                                                            \
    }

    // one stream-phase: compute stream S at step t from HQ_CUR; prefetch HQ_NXT
#define PHASE(S, HQ_CUR, HQ_NXT)                                                    \
    {                                                                               \
        /* (a) readiness + prefetch next stream's h */                              \
        if ((S) < 3) {                                                              \
            if (t > 0) { WAIT((S) + 1, t - 1); }                                    \
            LOAD_H(par, (S) + 1, HQ_NXT);                                           \
        } else if (t + 1 < T_) {                                                    \
            WAIT(0, t);                                                             \
            LOAD_H(par ^ 1, 0, HQ_NXT);                                             \
        }                                                                           \
        /* (b) zero gate accumulators */                                            \
        {                                                                           \
            float* lg = (float*)lds_g;                                              \
            lg[tid] = 0.f; lg[tid + 512] = 0.f;                                     \
            lg[tid + 1024] = 0.f; lg[tid + 1536] = 0.f;                             \
        }                                                                           \
        /* (c) MFMA partials, 4 gates x k-quarter */                                \
        f32x4 acc[4] = {};                                                          \
        _Pragma("unroll")                                                           \
        for (int kk = 0; kk < 8; ++kk) {                                            \
            union { unsigned long long q[2]; bf16x8 v; } ua;                        \
            ua.q[0] = HQ_CUR[2*kk]; ua.q[1] = HQ_CUR[2*kk+1];                       \
            _Pragma("unroll")                                                       \
            for (int g4 = 0; g4 < 4; ++g4) {                                        \
                bf16x8 bb = *reinterpret_cast<const bf16x8*>(                       \
                    bwave + kk * 2048 + g4 * 128);                                  \
                acc[g4] = __builtin_amdgcn_mfma_f32_16x16x32_bf16(                  \
                    ua.v, bb, acc[g4], 0, 0, 0);                                    \
            }                                                                       \
        }                                                                           \
        __syncthreads();   /* zeros visible */                                      \
        _Pragma("unroll")                                                           \
        for (int g4 = 0; g4 < 4; ++g4)                                              \
            _Pragma("unroll")                                                       \
            for (int r = 0; r < 4; ++r)                                             \
                atomicAdd(&lds_g[g4][mh * 16 + lkidx * 4 + r][lr], acc[g4][r]);     \
        __syncthreads();                                                            \
        /* (f) fused elementwise */                                                 \
        size_t eoff = (size_t)((S) * 32 + erow) * H_ + n0 + ecol;                   \
        float gi = lds_g[0][erow][ecol] + bf2f(gxr[S][0]);                          \
        float gf = lds_g[1][erow][ecol] + bf2f(gxr[S][1]);                          \
        float gg = lds_g[2][erow][ecol] + bf2f(gxr[S][2]);                          \
        float go = lds_g[3][erow][ecol] + bf2f(gxr[S][3]);                          \
        float iv = sigmoidf_(gi);                                                   \
        float fv = sigmoidf_(gf);                                                   \
        float gv = tanhf_(gg);                                                      \
        float ov = sigmoidf_(go);                                                   \
        c[S] = fv * c[S] + iv * gv;                                                 \
        float hn = ov * tanhf_(c[S]);                                               \
        ys[(size_t)t * BH + eoff] = hn;                                             \
        {                                                                           \
            unsigned short* hbn = hbuf + (size_t)(par ^ 1) * BH;                    \
            float hn_o = __shfl_xor(hn, 1);                                         \
            if ((tid & 1) == 0) {                                                   \
                unsigned u = (unsigned)f2bf(hn) | (((unsigned)f2bf(hn_o)) << 16);   \
                __hip_atomic_store((unsigned*)(hbn + eoff), u,                      \
                                   __ATOMIC_RELAXED, __HIP_MEMORY_SCOPE_AGENT);     \
            }                                                                       \
        }                                                                           \
        if (t == T_ - 1) { hT[eoff] = hn; cT[eoff] = c[S]; }                        \
        if (t + 1 < T_) {                                                           \
            const unsigned short* p = gx + (size_t)(t + 1) * B_ * G_                \
                + (size_t)((S) * 32 + erow) * G_ + n0 + ecol;                       \
            gxr[S][0] = p[0]; gxr[S][1] = p[1024];                                  \
            gxr[S][2] = p[2048]; gxr[S][3] = p[3072];                               \
        }                                                                           \
        __syncthreads();   /* drain h stores before arrive */                       \
        ARRIVE(S, t);                                                               \
    }

    LOAD_H(0, 0, hqA);

    for (int t = 0; t < T_; ++t) {
        const int par = t & 1;
        PHASE(0, hqA, hqB);
        PHASE(1, hqB, hqA);
        PHASE(2, hqA, hqB);
        PHASE(3, hqB, hqA);
    }
#undef PHASE
#undef WAIT
#undef ARRIVE
#undef LOAD_H
}

extern "C" void kernel_launch(void* const* d_in, const int* in_sizes, int n_in,
                              void* d_out, int out_size, void* d_ws, size_t ws_size,
                              hipStream_t stream)
{
    const float* x   = (const float*)d_in[0];
    const float* h0  = (const float*)d_in[1];
    const float* c0  = (const float*)d_in[2];
    const float* Wih = (const float*)d_in[3];
    const float* Whh = (const float*)d_in[4];
    const float* bih = (const float*)d_in[5];
    const float* bhh = (const float*)d_in[6];

    // workspace layout (bytes)
    char* ws = (char*)d_ws;
    unsigned short* gx   = (unsigned short*)(ws);                 // 256 MB
    unsigned short* xb   = (unsigned short*)(ws + 268435456);     //  64 MB
    unsigned short* wihb = (unsigned short*)(ws + 335544320);     //   8 MB
    unsigned short* whhb = (unsigned short*)(ws + 343932928);     //   8 MB
    unsigned short* hbuf = (unsigned short*)(ws + 352321536);     // 512 KB: h dbuf bf16
    float*          bias = (float*)(ws + 352845824);              //  16 KB
    unsigned*       bar  = (unsigned*)(ws + 352862208);           //   8 KB barrier (4 streams x 2KB)

    float* out = (float*)d_out;
    float* ys = out;                           // [256][128][1024]
    float* hT = out + (size_t)TB * H_;         // [128][1024]
    float* cT = hT + BH;                       // [128][1024]

    hipMemsetAsync(bar, 0, 8192, stream);
    cvt_kernel<<<2048, 256, 0, stream>>>(x,   xb,   TB * I_);
    cvt_kernel<<<512,  256, 0, stream>>>(Wih, wihb, G_ * I_);
    cvt_kernel<<<512,  256, 0, stream>>>(Whh, whhb, G_ * H_);
    cvt_kernel<<<128,  256, 0, stream>>>(h0,  hbuf, BH);   // hbuf[0] = h0
    bias_kernel<<<16, 256, 0, stream>>>(bih, bhh, bias);

    pregemm<<<8192, 256, 0, stream>>>(xb, wihb, bias, gx);

    lstm_recur4<<<64, 512, 0, stream>>>(whhb, gx, c0, hbuf, ys, hT, cT, bar);
}

// Round 7
// 4833.660 us; speedup vs baseline: 3.5357x; 3.5357x over previous
//
#include <hip/hip_runtime.h>

#define T_ 256
#define B_ 128
#define I_ 1024
#define H_ 1024
#define G_ 4096   // 4*H
#define BH (B_*H_)   // 131072
#define TB (T_*B_)   // 32768

typedef float f32x4 __attribute__((ext_vector_type(4)));
typedef short bf16x8 __attribute__((ext_vector_type(8)));

__device__ inline unsigned short f2bf(float f) {
    union { float f; unsigned int u; } v; v.f = f;
    unsigned int u = v.u;
    unsigned int r = (u + 0x7fffu + ((u >> 16) & 1u)) >> 16;
    return (unsigned short)r;
}
__device__ inline float bf2f(unsigned short s) {
    union { unsigned int u; float f; } v; v.u = ((unsigned int)s) << 16;
    return v.f;
}
__device__ inline float sigmoidf_(float x) { return 1.0f / (1.0f + __expf(-x)); }
__device__ inline float tanhf_(float x) {
    x = fminf(15.0f, fmaxf(-15.0f, x));
    float e = __expf(2.0f * x);
    return (e - 1.0f) / (e + 1.0f);
}

// ---------------- convert fp32 -> bf16 (vectorized) ----------------
__global__ void cvt_kernel(const float* __restrict__ src, unsigned short* __restrict__ dst, int n) {
    int i = (blockIdx.x * blockDim.x + threadIdx.x) * 4;
    int stride = gridDim.x * blockDim.x * 4;
    for (; i < n; i += stride) {
        float4 v = *reinterpret_cast<const float4*>(src + i);
        ushort4 o;
        o.x = f2bf(v.x); o.y = f2bf(v.y); o.z = f2bf(v.z); o.w = f2bf(v.w);
        *reinterpret_cast<ushort4*>(dst + i) = o;
    }
}

__global__ void bias_kernel(const float* __restrict__ a, const float* __restrict__ b, float* __restrict__ out) {
    int i = blockIdx.x * blockDim.x + threadIdx.x;
    if (i < G_) out[i] = a[i] + b[i];
}

// ---------------- pre-GEMM: gates_x = x @ Wih^T + bias  (bf16 out) ----------------
__global__ __launch_bounds__(256) void pregemm(
    const unsigned short* __restrict__ xb,   // [32768][1024] bf16
    const unsigned short* __restrict__ wih,  // [4096][1024] bf16
    const float* __restrict__ bias,          // [4096]
    unsigned short* __restrict__ gx)         // [32768][4096] bf16
{
    int wgid = (blockIdx.x & 7) * 1024 + (blockIdx.x >> 3);
    int mg = wgid & 255;
    int ng = wgid >> 8;
    int m0 = mg * 128, n0 = ng * 128;
    int tid = threadIdx.x;
    int w = tid >> 6, l = tid & 63;
    int qm = (w >> 1) * 64, qn = (w & 1) * 64;
    int lr = l & 15, lk = (l >> 4) * 8, lq = l >> 4;

    const unsigned short* ap = xb  + (size_t)(m0 + qm + lr) * I_ + lk;
    const unsigned short* bp = wih + (size_t)(n0 + qn + lr) * I_ + lk;

    f32x4 acc[4][4] = {};
    #pragma unroll 4
    for (int kk = 0; kk < 32; ++kk) {
        bf16x8 a[4], b[4];
        #pragma unroll
        for (int mt = 0; mt < 4; ++mt)
            a[mt] = *reinterpret_cast<const bf16x8*>(ap + (size_t)mt * 16 * I_ + kk * 32);
        #pragma unroll
        for (int nt = 0; nt < 4; ++nt)
            b[nt] = *reinterpret_cast<const bf16x8*>(bp + (size_t)nt * 16 * I_ + kk * 32);
        #pragma unroll
        for (int mt = 0; mt < 4; ++mt)
            #pragma unroll
            for (int nt = 0; nt < 4; ++nt)
                acc[mt][nt] = __builtin_amdgcn_mfma_f32_16x16x32_bf16(a[mt], b[nt], acc[mt][nt], 0, 0, 0);
    }
    #pragma unroll
    for (int mt = 0; mt < 4; ++mt) {
        #pragma unroll
        for (int nt = 0; nt < 4; ++nt) {
            #pragma unroll
            for (int r = 0; r < 4; ++r) {
                int m = m0 + qm + mt * 16 + lq * 4 + r;
                int n = n0 + qn + nt * 16 + lr;
                gx[(size_t)m * G_ + n] = f2bf(acc[mt][nt][r] + bias[n]);
            }
        }
    }
}

// ---------------- per-group barrier: 64 blocks, 8 leaves x 8 (r5-proven) ----------------
__device__ __forceinline__ void group_barrier(unsigned* gbar, int step, int ing) {
    __syncthreads();   // drains vmcnt: all sc1 h-stores at coherence point
    if (threadIdx.x == 0) {
        unsigned target = (unsigned)(step * 8 + 7);
        unsigned old = __hip_atomic_fetch_add(gbar + (ing & 7) * 32, 1u,
                                              __ATOMIC_RELAXED, __HIP_MEMORY_SCOPE_AGENT);
        if (old == target) {
            unsigned mold = __hip_atomic_fetch_add(gbar + 256, 1u,
                                                   __ATOMIC_RELAXED, __HIP_MEMORY_SCOPE_AGENT);
            if (mold == target) {
                __hip_atomic_store(gbar + 288, (unsigned)(step + 1),
                                   __ATOMIC_RELAXED, __HIP_MEMORY_SCOPE_AGENT);
            }
        }
        while (__hip_atomic_load(gbar + 288, __ATOMIC_RELAXED, __HIP_MEMORY_SCOPE_AGENT)
               < (unsigned)(step + 1)) {
            __builtin_amdgcn_s_sleep(1);
        }
    }
    __syncthreads();
}

// ---------------- persistent recurrent kernel: all 256 steps ----------------
// r5 structure; ONLY change: h loads are pipelined inline-asm global_load_dwordx4
// with sc0 sc1 (L1+L2 bypass -> coherence point), one vmcnt(0) for all 8.
__global__ __launch_bounds__(512) void lstm_recur(
    const unsigned short* __restrict__ whh,   // [4096][1024] bf16
    const unsigned short* __restrict__ gx,    // [32768][4096] bf16
    const float* __restrict__ c0,             // [128][1024]
    unsigned short* __restrict__ hbuf,        // [2][128][1024] bf16 (buf 0 = h0)
    float* __restrict__ ys,                   // [256][128][1024]
    float* __restrict__ hT, float* __restrict__ cT,
    unsigned* __restrict__ bar)
{
    __shared__ unsigned short whh_lds[8192 * 8];   // 128 KB: [ck][row][8]
    __shared__ float lds_g[4][32][16];             // 8 KB gate accumulators

    const int bid = blockIdx.x;
    const int mg  = (bid & 7) >> 1;               // group / m-tile, pinned to XCD pair
    const int ing = (bid >> 3) * 2 + (bid & 1);   // in-group index = ng, 0..63
    const int m0 = mg * 32, n0 = ing * 16;
    unsigned* gbar = bar + mg * 512;

    const int tid = threadIdx.x;
    const int w = tid >> 6, l = tid & 63;
    const int mh = w >> 2, kq = w & 3;            // wave roles: m-half, k-quarter
    const int lr = l & 15, lkidx = l >> 4;

    // ---- stage Whh slice into LDS once (k-major, r5-verified) ----
    for (int it = 0; it < 16; ++it) {
        int idx = it * 512 + tid;
        int row = idx >> 7;
        int ck  = idx & 127;
        int gg = row >> 4, cc = row & 15;
        bf16x8 v = *reinterpret_cast<const bf16x8*>(
            whh + (size_t)(gg * 1024 + n0 + cc) * H_ + ck * 8);
        *reinterpret_cast<bf16x8*>(whh_lds + ((size_t)ck * 64 + row) * 8) = v;
    }
    __syncthreads();

    const unsigned short* bwave = whh_lds + (((size_t)(kq * 32 + lkidx)) * 64 + lr) * 8;

    const int erow = tid >> 4, ecol = tid & 15;
    const size_t eoff = (size_t)(m0 + erow) * H_ + n0 + ecol;
    float c = c0[eoff];
    const unsigned short* gxp = gx + (size_t)(m0 + erow) * G_ + n0 + ecol;

    // A-row byte base (within a parity buffer): rows m0+mh*16+lr, k-quarter kq
    const size_t hrow = (size_t)(m0 + mh * 16 + lr) * H_ + kq * 256;

    unsigned short gx0 = gxp[0], gx1 = gxp[1024], gx2 = gxp[2048], gx3 = gxp[3072];

    for (int t = 0; t < T_; ++t) {
        // ---- pipelined h loads: 8x global_load_dwordx4 sc0 sc1, one wait ----
        const char* hpb = (const char*)hbuf
            + ((size_t)(t & 1) * BH + hrow) * 2 + lkidx * 16;
        bf16x8 hv0, hv1, hv2, hv3, hv4, hv5, hv6, hv7;
        asm volatile("global_load_dwordx4 %0, %1, off sc0 sc1"             : "=&v"(hv0) : "v"(hpb));
        asm volatile("global_load_dwordx4 %0, %1, off offset:64 sc0 sc1"   : "=&v"(hv1) : "v"(hpb));
        asm volatile("global_load_dwordx4 %0, %1, off offset:128 sc0 sc1"  : "=&v"(hv2) : "v"(hpb));
        asm volatile("global_load_dwordx4 %0, %1, off offset:192 sc0 sc1"  : "=&v"(hv3) : "v"(hpb));
        asm volatile("global_load_dwordx4 %0, %1, off offset:256 sc0 sc1"  : "=&v"(hv4) : "v"(hpb));
        asm volatile("global_load_dwordx4 %0, %1, off offset:320 sc0 sc1"  : "=&v"(hv5) : "v"(hpb));
        asm volatile("global_load_dwordx4 %0, %1, off offset:384 sc0 sc1"  : "=&v"(hv6) : "v"(hpb));
        asm volatile("global_load_dwordx4 %0, %1, off offset:448 sc0 sc1"  : "=&v"(hv7) : "v"(hpb));

        // zero gate accumulators while loads fly
        {
            float* lg = (float*)lds_g;
            lg[tid] = 0.f; lg[tid + 512] = 0.f; lg[tid + 1024] = 0.f; lg[tid + 1536] = 0.f;
        }

        asm volatile("s_waitcnt vmcnt(0)" ::: "memory");
        __builtin_amdgcn_sched_barrier(0);

        // ---- MFMA: partials for all 4 gates over this wave's k-quarter ----
        f32x4 acc[4] = {};
#define MFMA_K(KK, HV)                                                              \
        {                                                                           \
            _Pragma("unroll")                                                       \
            for (int g4 = 0; g4 < 4; ++g4) {                                        \
                bf16x8 bb = *reinterpret_cast<const bf16x8*>(                       \
                    bwave + (KK) * 2048 + g4 * 128);                                \
                acc[g4] = __builtin_amdgcn_mfma_f32_16x16x32_bf16(                  \
                    HV, bb, acc[g4], 0, 0, 0);                                      \
            }                                                                       \
        }
        MFMA_K(0, hv0) MFMA_K(1, hv1) MFMA_K(2, hv2) MFMA_K(3, hv3)
        MFMA_K(4, hv4) MFMA_K(5, hv5) MFMA_K(6, hv6) MFMA_K(7, hv7)
#undef MFMA_K
        __syncthreads();   // zeros visible before ds_add

        #pragma unroll
        for (int g4 = 0; g4 < 4; ++g4)
            #pragma unroll
            for (int r = 0; r < 4; ++r)
                atomicAdd(&lds_g[g4][mh * 16 + lkidx * 4 + r][lr], acc[g4][r]);
        __syncthreads();

        // ---- fused elementwise ----
        float gi = lds_g[0][erow][ecol] + bf2f(gx0);
        float gf = lds_g[1][erow][ecol] + bf2f(gx1);
        float gg = lds_g[2][erow][ecol] + bf2f(gx2);
        float go = lds_g[3][erow][ecol] + bf2f(gx3);
        float iv = sigmoidf_(gi);
        float fv = sigmoidf_(gf);
        float gv = tanhf_(gg);
        float ov = sigmoidf_(go);
        c = fv * c + iv * gv;
        float hn = ov * tanhf_(c);

        ys[(size_t)t * BH + eoff] = hn;

        unsigned short* hbn = hbuf + (size_t)((t + 1) & 1) * BH;
        float hn_o = __shfl_xor(hn, 1);
        if ((tid & 1) == 0) {
            unsigned u = (unsigned)f2bf(hn) | (((unsigned)f2bf(hn_o)) << 16);
            __hip_atomic_store((unsigned*)(hbn + eoff), u,
                               __ATOMIC_RELAXED, __HIP_MEMORY_SCOPE_AGENT);
        }
        if (t == T_ - 1) { hT[eoff] = hn; cT[eoff] = c; }

        if (t + 1 < T_) {
            const unsigned short* p = gxp + (size_t)(t + 1) * B_ * G_;
            gx0 = p[0]; gx1 = p[1024]; gx2 = p[2048]; gx3 = p[3072];
            group_barrier(gbar, t, ing);
        }
    }
}

extern "C" void kernel_launch(void* const* d_in, const int* in_sizes, int n_in,
                              void* d_out, int out_size, void* d_ws, size_t ws_size,
                              hipStream_t stream)
{
    const float* x   = (const float*)d_in[0];
    const float* h0  = (const float*)d_in[1];
    const float* c0  = (const float*)d_in[2];
    const float* Wih = (const float*)d_in[3];
    const float* Whh = (const float*)d_in[4];
    const float* bih = (const float*)d_in[5];
    const float* bhh = (const float*)d_in[6];

    // workspace layout (bytes)
    char* ws = (char*)d_ws;
    unsigned short* gx   = (unsigned short*)(ws);                 // 256 MB
    unsigned short* xb   = (unsigned short*)(ws + 268435456);     //  64 MB
    unsigned short* wihb = (unsigned short*)(ws + 335544320);     //   8 MB
    unsigned short* whhb = (unsigned short*)(ws + 343932928);     //   8 MB
    unsigned short* hbuf = (unsigned short*)(ws + 352321536);     // 512 KB: h dbuf bf16
    float*          bias = (float*)(ws + 352845824);              //  16 KB
    unsigned*       bar  = (unsigned*)(ws + 352862208);           //   8 KB barrier (4 groups x 2KB)

    float* out = (float*)d_out;
    float* ys = out;                           // [256][128][1024]
    float* hT = out + (size_t)TB * H_;         // [128][1024]
    float* cT = hT + BH;                       // [128][1024]

    hipMemsetAsync(bar, 0, 8192, stream);
    cvt_kernel<<<2048, 256, 0, stream>>>(x,   xb,   TB * I_);
    cvt_kernel<<<512,  256, 0, stream>>>(Wih, wihb, G_ * I_);
    cvt_kernel<<<512,  256, 0, stream>>>(Whh, whhb, G_ * H_);
    cvt_kernel<<<128,  256, 0, stream>>>(h0,  hbuf, BH);   // hbuf[0] = h0
    bias_kernel<<<16, 256, 0, stream>>>(bih, bhh, bias);

    pregemm<<<8192, 256, 0, stream>>>(xb, wihb, bias, gx);

    lstm_recur<<<256, 512, 0, stream>>>(whhb, gx, c0, hbuf, ys, hT, cT, bar);
}

// Round 8
// 4345.486 us; speedup vs baseline: 3.9329x; 1.1123x over previous
//
#include <hip/hip_runtime.h>

#define T_ 256
#define B_ 128
#define I_ 1024
#define H_ 1024
#define G_ 4096   // 4*H
#define BH (B_*H_)   // 131072
#define TB (T_*B_)   // 32768

typedef float f32x4 __attribute__((ext_vector_type(4)));
typedef short bf16x8 __attribute__((ext_vector_type(8)));

__device__ inline unsigned short f2bf(float f) {
    union { float f; unsigned int u; } v; v.f = f;
    unsigned int u = v.u;
    unsigned int r = (u + 0x7fffu + ((u >> 16) & 1u)) >> 16;
    return (unsigned short)r;
}
__device__ inline float bf2f(unsigned short s) {
    union { unsigned int u; float f; } v; v.u = ((unsigned int)s) << 16;
    return v.f;
}
__device__ inline float sigmoidf_(float x) { return 1.0f / (1.0f + __expf(-x)); }
__device__ inline float tanhf_(float x) {
    x = fminf(15.0f, fmaxf(-15.0f, x));
    float e = __expf(2.0f * x);
    return (e - 1.0f) / (e + 1.0f);
}

__device__ __forceinline__ void gload16(const unsigned short* g, unsigned short* l) {
    __builtin_amdgcn_global_load_lds(
        (const __attribute__((address_space(1))) void*)g,
        (__attribute__((address_space(3))) void*)l,
        16, 0, 0);
}

// ---------------- convert fp32 -> bf16 (vectorized) ----------------
__global__ void cvt_kernel(const float* __restrict__ src, unsigned short* __restrict__ dst, int n) {
    int i = (blockIdx.x * blockDim.x + threadIdx.x) * 4;
    int stride = gridDim.x * blockDim.x * 4;
    for (; i < n; i += stride) {
        float4 v = *reinterpret_cast<const float4*>(src + i);
        ushort4 o;
        o.x = f2bf(v.x); o.y = f2bf(v.y); o.z = f2bf(v.z); o.w = f2bf(v.w);
        *reinterpret_cast<ushort4*>(dst + i) = o;
    }
}

__global__ void bias_kernel(const float* __restrict__ a, const float* __restrict__ b, float* __restrict__ out) {
    int i = blockIdx.x * blockDim.x + threadIdx.x;
    if (i < G_) out[i] = a[i] + b[i];
}

// ---------------- pre-GEMM v2 (m97 structure): gates_x = x @ Wih^T + bias ----------------
// 128x128 tile, BK=64, 4 waves, double-buffered LDS staged via global_load_lds w=16.
__global__ __launch_bounds__(256, 2) void pregemm(
    const unsigned short* __restrict__ xb,   // [32768][1024] bf16
    const unsigned short* __restrict__ wih,  // [4096][1024] bf16
    const float* __restrict__ bias,          // [4096]
    unsigned short* __restrict__ gx)         // [32768][4096] bf16
{
    __shared__ unsigned short Ab[2][128 * 64];   // 16KB x2
    __shared__ unsigned short Bb[2][128 * 64];   // 16KB x2

    int swz = (blockIdx.x & 7) * 1024 + (blockIdx.x >> 3);   // XCD-chunked, bijective
    int mg = swz & 255;      // fast index: same ng across an XCD pass -> B-panel L2-resident
    int ng = swz >> 8;
    int m0 = mg * 128, n0 = ng * 128;
    int tid = threadIdx.x;
    int w = tid >> 6, l = tid & 63;
    int qm = (w >> 1) * 64, qn = (w & 1) * 64;
    int lr = l & 15, lkidx = (l >> 4);

    // staging geometry: 1024 16B-chunks per tile; wave w, iter it -> chunks [(w*4+it)*64 .. +64)
    int srow = ((w * 4) * 64 + l) >> 3;      // base row for it=0 (advances by 8 per it)
    int sk8  = l & 7;

#define STAGE(BUF, KT)                                                              \
    {                                                                               \
        _Pragma("unroll")                                                           \
        for (int it = 0; it < 4; ++it) {                                            \
            int row = srow + it * 8;                                                \
            gload16(xb  + (size_t)(m0 + row) * I_ + (KT) * 64 + sk8 * 8,            \
                    &Ab[BUF][(w * 4 + it) * 512]);                                  \
            gload16(wih + (size_t)(n0 + row) * I_ + (KT) * 64 + sk8 * 8,            \
                    &Bb[BUF][(w * 4 + it) * 512]);                                  \
        }                                                                           \
    }

    f32x4 acc[4][4] = {};
    int buf = 0;
    STAGE(0, 0)
    __syncthreads();

    for (int kt = 0; kt < 16; ++kt) {
        if (kt + 1 < 16) STAGE(buf ^ 1, kt + 1)
        #pragma unroll
        for (int kk = 0; kk < 2; ++kk) {
            bf16x8 a[4], b[4];
            #pragma unroll
            for (int mt = 0; mt < 4; ++mt)
                a[mt] = *reinterpret_cast<const bf16x8*>(
                    &Ab[buf][(qm + mt * 16 + lr) * 64 + kk * 32 + lkidx * 8]);
            #pragma unroll
            for (int nt = 0; nt < 4; ++nt)
                b[nt] = *reinterpret_cast<const bf16x8*>(
                    &Bb[buf][(qn + nt * 16 + lr) * 64 + kk * 32 + lkidx * 8]);
            #pragma unroll
            for (int mt = 0; mt < 4; ++mt)
                #pragma unroll
                for (int nt = 0; nt < 4; ++nt)
                    acc[mt][nt] = __builtin_amdgcn_mfma_f32_16x16x32_bf16(
                        a[mt], b[nt], acc[mt][nt], 0, 0, 0);
        }
        __syncthreads();
        buf ^= 1;
    }
#undef STAGE

    int lq = l >> 4;
    #pragma unroll
    for (int mt = 0; mt < 4; ++mt) {
        #pragma unroll
        for (int nt = 0; nt < 4; ++nt) {
            #pragma unroll
            for (int r = 0; r < 4; ++r) {
                int m = m0 + qm + mt * 16 + lq * 4 + r;
                int n = n0 + qn + nt * 16 + lr;
                gx[(size_t)m * G_ + n] = f2bf(acc[mt][nt][r] + bias[n]);
            }
        }
    }
}

// ---------------- persistent recurrent kernel: all 256 steps ----------------
// r5/r7 compute body. New sync: flat leaf-only barrier, fire-and-forget arrive,
// per-wave poll of exactly the 2 leaves covering its k-quarter producers.
// Group mg (64 blocks): leaves at bar[mg*32 .. +7]; leaf j = blocks ing in [8j,8j+8)
// = h-cols [128j, 128j+128). Wave kq consumes cols [256kq,+256) = leaves {2kq,2kq+1}.
__global__ __launch_bounds__(512) void lstm_recur(
    const unsigned short* __restrict__ whh,   // [4096][1024] bf16
    const unsigned short* __restrict__ gx,    // [32768][4096] bf16
    const float* __restrict__ c0,             // [128][1024]
    unsigned short* __restrict__ hbuf,        // [2][128][1024] bf16 (buf 0 = h0)
    float* __restrict__ ys,                   // [256][128][1024]
    float* __restrict__ hT, float* __restrict__ cT,
    unsigned* __restrict__ bar)
{
    __shared__ unsigned short whh_lds[8192 * 8];   // 128 KB: [ck][row][8]
    __shared__ float lds_g[4][32][16];             // 8 KB gate accumulators

    const int bid = blockIdx.x;
    const int mg  = (bid & 7) >> 1;               // group / m-tile, pinned to XCD pair
    const int ing = (bid >> 3) * 2 + (bid & 1);   // in-group index = ng, 0..63
    const int m0 = mg * 32, n0 = ing * 16;

    const int tid = threadIdx.x;
    const int w = tid >> 6, l = tid & 63;
    const int mh = w >> 2, kq = w & 3;            // wave roles: m-half, k-quarter
    const int lr = l & 15, lkidx = l >> 4;

    const unsigned* pollw = bar + mg * 32 + 2 * kq;       // this wave's 2 leaves
    unsigned* leafw = bar + mg * 32 + (ing >> 3);         // this block's arrive leaf

    // ---- stage Whh slice into LDS once (k-major, r5-verified) ----
    for (int it = 0; it < 16; ++it) {
        int idx = it * 512 + tid;
        int row = idx >> 7;
        int ck  = idx & 127;
        int gg = row >> 4, cc = row & 15;
        bf16x8 v = *reinterpret_cast<const bf16x8*>(
            whh + (size_t)(gg * 1024 + n0 + cc) * H_ + ck * 8);
        *reinterpret_cast<bf16x8*>(whh_lds + ((size_t)ck * 64 + row) * 8) = v;
    }
    __syncthreads();

    const unsigned short* bwave = whh_lds + (((size_t)(kq * 32 + lkidx)) * 64 + lr) * 8;

    const int erow = tid >> 4, ecol = tid & 15;
    const size_t eoff = (size_t)(m0 + erow) * H_ + n0 + ecol;
    float c = c0[eoff];
    const unsigned short* gxp = gx + (size_t)(m0 + erow) * G_ + n0 + ecol;

    const size_t hrow = (size_t)(m0 + mh * 16 + lr) * H_ + kq * 256;

    unsigned short gx0 = gxp[0], gx1 = gxp[1024], gx2 = gxp[2048], gx3 = gxp[3072];

    for (int t = 0; t < T_; ++t) {
        // ---- per-wave poll: my 2 leaves >= 8t (producers of my k-quarter done) ----
        if (t > 0) {
            unsigned tgt = 8u * (unsigned)t;
            while (true) {
                unsigned long long lv;
                asm volatile("global_load_dwordx2 %0, %1, off sc0 sc1"
                             : "=&v"(lv) : "v"(pollw));
                asm volatile("s_waitcnt vmcnt(0)" ::: "memory");
                if ((unsigned)lv >= tgt && (unsigned)(lv >> 32) >= tgt) break;
                __builtin_amdgcn_s_sleep(1);
            }
        }

        // ---- pipelined h loads: 8x global_load_dwordx4 sc0 sc1, one wait ----
        const char* hpb = (const char*)hbuf
            + ((size_t)(t & 1) * BH + hrow) * 2 + lkidx * 16;
        bf16x8 hv0, hv1, hv2, hv3, hv4, hv5, hv6, hv7;
        asm volatile("global_load_dwordx4 %0, %1, off sc0 sc1"             : "=&v"(hv0) : "v"(hpb));
        asm volatile("global_load_dwordx4 %0, %1, off offset:64 sc0 sc1"   : "=&v"(hv1) : "v"(hpb));
        asm volatile("global_load_dwordx4 %0, %1, off offset:128 sc0 sc1"  : "=&v"(hv2) : "v"(hpb));
        asm volatile("global_load_dwordx4 %0, %1, off offset:192 sc0 sc1"  : "=&v"(hv3) : "v"(hpb));
        asm volatile("global_load_dwordx4 %0, %1, off offset:256 sc0 sc1"  : "=&v"(hv4) : "v"(hpb));
        asm volatile("global_load_dwordx4 %0, %1, off offset:320 sc0 sc1"  : "=&v"(hv5) : "v"(hpb));
        asm volatile("global_load_dwordx4 %0, %1, off offset:384 sc0 sc1"  : "=&v"(hv6) : "v"(hpb));
        asm volatile("global_load_dwordx4 %0, %1, off offset:448 sc0 sc1"  : "=&v"(hv7) : "v"(hpb));

        // zero gate accumulators while loads fly
        {
            float* lg = (float*)lds_g;
            lg[tid] = 0.f; lg[tid + 512] = 0.f; lg[tid + 1024] = 0.f; lg[tid + 1536] = 0.f;
        }

        asm volatile("s_waitcnt vmcnt(0)" ::: "memory");
        __builtin_amdgcn_sched_barrier(0);

        // ---- MFMA: partials for all 4 gates over this wave's k-quarter ----
        f32x4 acc[4] = {};
#define MFMA_K(KK, HV)                                                              \
        {                                                                           \
            _Pragma("unroll")                                                       \
            for (int g4 = 0; g4 < 4; ++g4) {                                        \
                bf16x8 bb = *reinterpret_cast<const bf16x8*>(                       \
                    bwave + (KK) * 2048 + g4 * 128);                                \
                acc[g4] = __builtin_amdgcn_mfma_f32_16x16x32_bf16(                  \
                    HV, bb, acc[g4], 0, 0, 0);                                      \
            }                                                                       \
        }
        MFMA_K(0, hv0) MFMA_K(1, hv1) MFMA_K(2, hv2) MFMA_K(3, hv3)
        MFMA_K(4, hv4) MFMA_K(5, hv5) MFMA_K(6, hv6) MFMA_K(7, hv7)
#undef MFMA_K
        __syncthreads();   // zeros visible before ds_add

        #pragma unroll
        for (int g4 = 0; g4 < 4; ++g4)
            #pragma unroll
            for (int r = 0; r < 4; ++r)
                atomicAdd(&lds_g[g4][mh * 16 + lkidx * 4 + r][lr], acc[g4][r]);
        __syncthreads();

        // ---- fused elementwise ----
        float gi = lds_g[0][erow][ecol] + bf2f(gx0);
        float gf = lds_g[1][erow][ecol] + bf2f(gx1);
        float gg = lds_g[2][erow][ecol] + bf2f(gx2);
        float go = lds_g[3][erow][ecol] + bf2f(gx3);
        float iv = sigmoidf_(gi);
        float fv = sigmoidf_(gf);
        float gv = tanhf_(gg);
        float ov = sigmoidf_(go);
        c = fv * c + iv * gv;
        float hn = ov * tanhf_(c);

        // h store first (critical path), then ys
        unsigned short* hbn = hbuf + (size_t)((t + 1) & 1) * BH;
        float hn_o = __shfl_xor(hn, 1);
        if ((tid & 1) == 0) {
            unsigned u = (unsigned)f2bf(hn) | (((unsigned)f2bf(hn_o)) << 16);
            __hip_atomic_store((unsigned*)(hbn + eoff), u,
                               __ATOMIC_RELAXED, __HIP_MEMORY_SCOPE_AGENT);
        }
        ys[(size_t)t * BH + eoff] = hn;
        if (t == T_ - 1) { hT[eoff] = hn; cT[eoff] = c; }

        // prefetch next step's gx (drains inside the barrier sync below)
        if (t + 1 < T_) {
            const unsigned short* p = gxp + (size_t)(t + 1) * B_ * G_;
            gx0 = p[0]; gx1 = p[1024]; gx2 = p[2048]; gx3 = p[3072];
        }

        __syncthreads();   // drain: h committed; lds_g reads done (safe to re-zero next iter)

        // fire-and-forget arrive (non-returning atomic -> no RMW-result stall)
        if (tid == 0 && t + 1 < T_) {
            unsigned one = 1u;
            asm volatile("global_atomic_add %0, %1, off"
                         :: "v"(leafw), "v"(one) : "memory");
        }
    }
}

extern "C" void kernel_launch(void* const* d_in, const int* in_sizes, int n_in,
                              void* d_out, int out_size, void* d_ws, size_t ws_size,
                              hipStream_t stream)
{
    const float* x   = (const float*)d_in[0];
    const float* h0  = (const float*)d_in[1];
    const float* c0  = (const float*)d_in[2];
    const float* Wih = (const float*)d_in[3];
    const float* Whh = (const float*)d_in[4];
    const float* bih = (const float*)d_in[5];
    const float* bhh = (const float*)d_in[6];

    // workspace layout (bytes)
    char* ws = (char*)d_ws;
    unsigned short* gx   = (unsigned short*)(ws);                 // 256 MB
    unsigned short* xb   = (unsigned short*)(ws + 268435456);     //  64 MB
    unsigned short* wihb = (unsigned short*)(ws + 335544320);     //   8 MB
    unsigned short* whhb = (unsigned short*)(ws + 343932928);     //   8 MB
    unsigned short* hbuf = (unsigned short*)(ws + 352321536);     // 512 KB: h dbuf bf16
    float*          bias = (float*)(ws + 352845824);              //  16 KB
    unsigned*       bar  = (unsigned*)(ws + 352862208);           //  barrier: 4 groups x 32 words

    float* out = (float*)d_out;
    float* ys = out;                           // [256][128][1024]
    float* hT = out + (size_t)TB * H_;         // [128][1024]
    float* cT = hT + BH;                       // [128][1024]

    hipMemsetAsync(bar, 0, 4096, stream);
    cvt_kernel<<<2048, 256, 0, stream>>>(x,   xb,   TB * I_);
    cvt_kernel<<<512,  256, 0, stream>>>(Wih, wihb, G_ * I_);
    cvt_kernel<<<512,  256, 0, stream>>>(Whh, whhb, G_ * H_);
    cvt_kernel<<<128,  256, 0, stream>>>(h0,  hbuf, BH);   // hbuf[0] = h0
    bias_kernel<<<16, 256, 0, stream>>>(bih, bhh, bias);

    pregemm<<<8192, 256, 0, stream>>>(xb, wihb, bias, gx);

    lstm_recur<<<256, 512, 0, stream>>>(whhb, gx, c0, hbuf, ys, hT, cT, bar);
}

// Round 11
// 4172.495 us; speedup vs baseline: 4.0959x; 1.0415x over previous
//
#include <hip/hip_runtime.h>

#define T_ 256
#define B_ 128
#define I_ 1024
#define H_ 1024
#define G_ 4096   // 4*H
#define BH (B_*H_)   // 131072
#define TB (T_*B_)   // 32768

typedef float f32x4 __attribute__((ext_vector_type(4)));
typedef short bf16x8 __attribute__((ext_vector_type(8)));
typedef int   i32x4  __attribute__((ext_vector_type(4)));

__device__ inline unsigned short f2bf(float f) {
    union { float f; unsigned int u; } v; v.f = f;
    unsigned int u = v.u;
    unsigned int r = (u + 0x7fffu + ((u >> 16) & 1u)) >> 16;
    return (unsigned short)r;
}
__device__ inline float bf2f(unsigned short s) {
    union { unsigned int u; float f; } v; v.u = ((unsigned int)s) << 16;
    return v.f;
}
__device__ inline float sigmoidf_(float x) { return 1.0f / (1.0f + __expf(-x)); }
__device__ inline float tanhf_(float x) {
    x = fminf(15.0f, fmaxf(-15.0f, x));
    float e = __expf(2.0f * x);
    return (e - 1.0f) / (e + 1.0f);
}

__device__ __forceinline__ void gload16(const unsigned short* g, unsigned short* l) {
    __builtin_amdgcn_global_load_lds(
        (const __attribute__((address_space(1))) void*)g,
        (__attribute__((address_space(3))) void*)l,
        16, 0, 0);
}

// ---------------- convert fp32 -> bf16 (vectorized) ----------------
__global__ void cvt_kernel(const float* __restrict__ src, unsigned short* __restrict__ dst, int n) {
    int i = (blockIdx.x * blockDim.x + threadIdx.x) * 4;
    int stride = gridDim.x * blockDim.x * 4;
    for (; i < n; i += stride) {
        float4 v = *reinterpret_cast<const float4*>(src + i);
        ushort4 o;
        o.x = f2bf(v.x); o.y = f2bf(v.y); o.z = f2bf(v.z); o.w = f2bf(v.w);
        *reinterpret_cast<ushort4*>(dst + i) = o;
    }
}

// h0 -> bf16 with tag bit0 = 0 (generation 0)
__global__ void cvt_h0_kernel(const float* __restrict__ src, unsigned short* __restrict__ dst, int n) {
    int i = (blockIdx.x * blockDim.x + threadIdx.x) * 4;
    int stride = gridDim.x * blockDim.x * 4;
    for (; i < n; i += stride) {
        float4 v = *reinterpret_cast<const float4*>(src + i);
        ushort4 o;
        o.x = f2bf(v.x) & 0xFFFE; o.y = f2bf(v.y) & 0xFFFE;
        o.z = f2bf(v.z) & 0xFFFE; o.w = f2bf(v.w) & 0xFFFE;
        *reinterpret_cast<ushort4*>(dst + i) = o;
    }
}

// buf1 init: tag-1 filler (0x0001 per bf16) so generation-0 consumers wait properly
__global__ void init_b1_kernel(unsigned* __restrict__ p) {
    int i = (blockIdx.x * blockDim.x + threadIdx.x) * 4;   // 16384 threads x 4 dwords
    i32x4 v = {0x00010001, 0x00010001, 0x00010001, 0x00010001};
    *reinterpret_cast<i32x4*>(p + i) = v;
}

__global__ void bias_kernel(const float* __restrict__ a, const float* __restrict__ b, float* __restrict__ out) {
    int i = blockIdx.x * blockDim.x + threadIdx.x;
    if (i < G_) out[i] = a[i] + b[i];
}

// ---------------- pre-GEMM (m97 structure, r8-proven, unchanged) ----------------
__global__ __launch_bounds__(256, 2) void pregemm(
    const unsigned short* __restrict__ xb,
    const unsigned short* __restrict__ wih,
    const float* __restrict__ bias,
    unsigned short* __restrict__ gx)
{
    __shared__ unsigned short Ab[2][128 * 64];
    __shared__ unsigned short Bb[2][128 * 64];

    int swz = (blockIdx.x & 7) * 1024 + (blockIdx.x >> 3);
    int mg = swz & 255;
    int ng = swz >> 8;
    int m0 = mg * 128, n0 = ng * 128;
    int tid = threadIdx.x;
    int w = tid >> 6, l = tid & 63;
    int qm = (w >> 1) * 64, qn = (w & 1) * 64;
    int lr = l & 15, lkidx = (l >> 4);

    int srow = ((w * 4) * 64 + l) >> 3;
    int sk8  = l & 7;

#define STAGE(BUF, KT)                                                              \
    {                                                                               \
        _Pragma("unroll")                                                           \
        for (int it = 0; it < 4; ++it) {                                            \
            int row = srow + it * 8;                                                \
            gload16(xb  + (size_t)(m0 + row) * I_ + (KT) * 64 + sk8 * 8,            \
                    &Ab[BUF][(w * 4 + it) * 512]);                                  \
            gload16(wih + (size_t)(n0 + row) * I_ + (KT) * 64 + sk8 * 8,            \
                    &Bb[BUF][(w * 4 + it) * 512]);                                  \
        }                                                                           \
    }

    f32x4 acc[4][4] = {};
    int buf = 0;
    STAGE(0, 0)
    __syncthreads();

    for (int kt = 0; kt < 16; ++kt) {
        if (kt + 1 < 16) STAGE(buf ^ 1, kt + 1)
        #pragma unroll
        for (int kk = 0; kk < 2; ++kk) {
            bf16x8 a[4], b[4];
            #pragma unroll
            for (int mt = 0; mt < 4; ++mt)
                a[mt] = *reinterpret_cast<const bf16x8*>(
                    &Ab[buf][(qm + mt * 16 + lr) * 64 + kk * 32 + lkidx * 8]);
            #pragma unroll
            for (int nt = 0; nt < 4; ++nt)
                b[nt] = *reinterpret_cast<const bf16x8*>(
                    &Bb[buf][(qn + nt * 16 + lr) * 64 + kk * 32 + lkidx * 8]);
            #pragma unroll
            for (int mt = 0; mt < 4; ++mt)
                #pragma unroll
                for (int nt = 0; nt < 4; ++nt)
                    acc[mt][nt] = __builtin_amdgcn_mfma_f32_16x16x32_bf16(
                        a[mt], b[nt], acc[mt][nt], 0, 0, 0);
        }
        __syncthreads();
        buf ^= 1;
    }
#undef STAGE

    int lq = l >> 4;
    #pragma unroll
    for (int mt = 0; mt < 4; ++mt) {
        #pragma unroll
        for (int nt = 0; nt < 4; ++nt) {
            #pragma unroll
            for (int r = 0; r < 4; ++r) {
                int m = m0 + qm + mt * 16 + lq * 4 + r;
                int n = n0 + qn + nt * 16 + lr;
                gx[(size_t)m * G_ + n] = f2bf(acc[mt][nt][r] + bias[n]);
            }
        }
    }
}

// ---------------- persistent recurrent kernel: all 256 steps ----------------
// r8 body, flag-free sync: h bf16 values carry generation parity in bit0.
// Consumer polls ITS OWN h granules (sc0 sc1, r8-proven path) until all 32 dwords
// show tag ((t>>1)&1); poll exit == data in registers. Producer stores with
// __hip_atomic_store AGENT (r8-proven) after setting bit0 = ((t+1)>>1)&1.
__global__ __launch_bounds__(512) void lstm_recur(
    const unsigned short* __restrict__ whh,   // [4096][1024] bf16
    const unsigned short* __restrict__ gx,    // [32768][4096] bf16
    const float* __restrict__ c0,             // [128][1024]
    unsigned short* __restrict__ hbuf,        // [2][128][1024] bf16 (buf0=h0 tag0, buf1=tag1 filler)
    float* __restrict__ ys,
    float* __restrict__ hT, float* __restrict__ cT)
{
    __shared__ unsigned short whh_lds[8192 * 8];   // 128 KB: [ck][row][8]
    __shared__ float lds_g[4][32][16];             // 8 KB gate accumulators

    const int bid = blockIdx.x;
    const int mg  = (bid & 7) >> 1;               // group / m-tile, pinned to XCD pair
    const int ing = (bid >> 3) * 2 + (bid & 1);   // in-group index, 0..63
    const int m0 = mg * 32, n0 = ing * 16;

    const int tid = threadIdx.x;
    const int w = tid >> 6, l = tid & 63;
    const int mh = w >> 2, kq = w & 3;            // wave roles: m-half, k-quarter
    const int lr = l & 15, lkidx = l >> 4;

    // ---- stage Whh slice into LDS once (k-major, r5-verified) ----
    for (int it = 0; it < 16; ++it) {
        int idx = it * 512 + tid;
        int row = idx >> 7;
        int ck  = idx & 127;
        int gg = row >> 4, cc = row & 15;
        bf16x8 v = *reinterpret_cast<const bf16x8*>(
            whh + (size_t)(gg * 1024 + n0 + cc) * H_ + ck * 8);
        *reinterpret_cast<bf16x8*>(whh_lds + ((size_t)ck * 64 + row) * 8) = v;
    }
    __syncthreads();

    const unsigned short* bwave = whh_lds + (((size_t)(kq * 32 + lkidx)) * 64 + lr) * 8;

    const int erow = tid >> 4, ecol = tid & 15;
    const size_t eoff = (size_t)(m0 + erow) * H_ + n0 + ecol;
    float c = c0[eoff];
    const unsigned short* gxp = gx + (size_t)(m0 + erow) * G_ + n0 + ecol;

    const size_t hrow = (size_t)(m0 + mh * 16 + lr) * H_ + kq * 256;

    unsigned short gx0 = gxp[0], gx1 = gxp[1024], gx2 = gxp[2048], gx3 = gxp[3072];

    for (int t = 0; t < T_; ++t) {
        // ---- tag-poll + load: re-load my 8 granules until all carry tag (t>>1)&1 ----
        const char* hpb = (const char*)hbuf
            + ((size_t)(t & 1) * BH + hrow) * 2 + lkidx * 16;
        const unsigned expw = ((unsigned)((t >> 1) & 1)) * 0x00010001u;
        i32x4 hv0, hv1, hv2, hv3, hv4, hv5, hv6, hv7;
        while (true) {
            asm volatile("global_load_dwordx4 %0, %1, off sc0 sc1"             : "=&v"(hv0) : "v"(hpb));
            asm volatile("global_load_dwordx4 %0, %1, off offset:64 sc0 sc1"   : "=&v"(hv1) : "v"(hpb));
            asm volatile("global_load_dwordx4 %0, %1, off offset:128 sc0 sc1"  : "=&v"(hv2) : "v"(hpb));
            asm volatile("global_load_dwordx4 %0, %1, off offset:192 sc0 sc1"  : "=&v"(hv3) : "v"(hpb));
            asm volatile("global_load_dwordx4 %0, %1, off offset:256 sc0 sc1"  : "=&v"(hv4) : "v"(hpb));
            asm volatile("global_load_dwordx4 %0, %1, off offset:320 sc0 sc1"  : "=&v"(hv5) : "v"(hpb));
            asm volatile("global_load_dwordx4 %0, %1, off offset:384 sc0 sc1"  : "=&v"(hv6) : "v"(hpb));
            asm volatile("global_load_dwordx4 %0, %1, off offset:448 sc0 sc1"  : "=&v"(hv7) : "v"(hpb));
            asm volatile("s_waitcnt vmcnt(0)" ::: "memory");
            __builtin_amdgcn_sched_barrier(0);
            unsigned bad = 0;
#define CHK(HV) bad |= (((unsigned)HV[0] ^ expw) | ((unsigned)HV[1] ^ expw) | \
                        ((unsigned)HV[2] ^ expw) | ((unsigned)HV[3] ^ expw)) & 0x00010001u;
            CHK(hv0) CHK(hv1) CHK(hv2) CHK(hv3) CHK(hv4) CHK(hv5) CHK(hv6) CHK(hv7)
#undef CHK
            if (__all((int)(bad == 0))) break;
            __builtin_amdgcn_s_sleep(4);
        }

        // zero gate accumulators
        {
            float* lg = (float*)lds_g;
            lg[tid] = 0.f; lg[tid + 512] = 0.f; lg[tid + 1024] = 0.f; lg[tid + 1536] = 0.f;
        }

        // ---- MFMA: partials for all 4 gates over this wave's k-quarter ----
        f32x4 acc[4] = {};
#define MFMA_K(KK, HV)                                                              \
        {                                                                           \
            bf16x8 av = __builtin_bit_cast(bf16x8, HV);                             \
            _Pragma("unroll")                                                       \
            for (int g4 = 0; g4 < 4; ++g4) {                                        \
                bf16x8 bb = *reinterpret_cast<const bf16x8*>(                       \
                    bwave + (KK) * 2048 + g4 * 128);                                \
                acc[g4] = __builtin_amdgcn_mfma_f32_16x16x32_bf16(                  \
                    av, bb, acc[g4], 0, 0, 0);                                      \
            }                                                                       \
        }
        MFMA_K(0, hv0) MFMA_K(1, hv1) MFMA_K(2, hv2) MFMA_K(3, hv3)
        MFMA_K(4, hv4) MFMA_K(5, hv5) MFMA_K(6, hv6) MFMA_K(7, hv7)
#undef MFMA_K
        __syncthreads();   // zeros visible before ds_add

        #pragma unroll
        for (int g4 = 0; g4 < 4; ++g4)
            #pragma unroll
            for (int r = 0; r < 4; ++r)
                atomicAdd(&lds_g[g4][mh * 16 + lkidx * 4 + r][lr], acc[g4][r]);
        __syncthreads();

        // ---- fused elementwise ----
        float gi = lds_g[0][erow][ecol] + bf2f(gx0);
        float gf = lds_g[1][erow][ecol] + bf2f(gx1);
        float gg = lds_g[2][erow][ecol] + bf2f(gx2);
        float go = lds_g[3][erow][ecol] + bf2f(gx3);
        float iv = sigmoidf_(gi);
        float fv = sigmoidf_(gf);
        float gv = tanhf_(gg);
        float ov = sigmoidf_(go);
        c = fv * c + iv * gv;
        float hn = ov * tanhf_(c);

        // ---- h store with generation tag in bit0 (fire-and-forget, r8-proven path) ----
        {
            const unsigned wtag = ((unsigned)(t + 1) >> 1) & 1u;
            unsigned us0 = ((unsigned)f2bf(hn) & 0xFFFEu) | wtag;
            float hn_o = __shfl_xor(hn, 1);
            unsigned us1 = ((unsigned)f2bf(hn_o) & 0xFFFEu) | wtag;
            if ((tid & 1) == 0) {
                unsigned u = us0 | (us1 << 16);
                unsigned short* hbn = hbuf + (size_t)((t + 1) & 1) * BH;
                __hip_atomic_store((unsigned*)(hbn + eoff), u,
                                   __ATOMIC_RELAXED, __HIP_MEMORY_SCOPE_AGENT);
            }
        }
        ys[(size_t)t * BH + eoff] = hn;
        if (t == T_ - 1) { hT[eoff] = hn; cT[eoff] = c; }

        // prefetch next step's gx
        if (t + 1 < T_) {
            const unsigned short* p = gxp + (size_t)(t + 1) * B_ * G_;
            gx0 = p[0]; gx1 = p[1024]; gx2 = p[2048]; gx3 = p[3072];
        }

        __syncthreads();   // lds_g reads done before next iteration re-zeros
    }
}

extern "C" void kernel_launch(void* const* d_in, const int* in_sizes, int n_in,
                              void* d_out, int out_size, void* d_ws, size_t ws_size,
                              hipStream_t stream)
{
    const float* x   = (const float*)d_in[0];
    const float* h0  = (const float*)d_in[1];
    const float* c0  = (const float*)d_in[2];
    const float* Wih = (const float*)d_in[3];
    const float* Whh = (const float*)d_in[4];
    const float* bih = (const float*)d_in[5];
    const float* bhh = (const float*)d_in[6];

    // workspace layout (bytes)
    char* ws = (char*)d_ws;
    unsigned short* gx   = (unsigned short*)(ws);                 // 256 MB
    unsigned short* xb   = (unsigned short*)(ws + 268435456);     //  64 MB
    unsigned short* wihb = (unsigned short*)(ws + 335544320);     //   8 MB
    unsigned short* whhb = (unsigned short*)(ws + 343932928);     //   8 MB
    unsigned short* hbuf = (unsigned short*)(ws + 352321536);     // 512 KB: h dbuf bf16 (tagged)
    float*          bias = (float*)(ws + 352845824);              //  16 KB

    float* out = (float*)d_out;
    float* ys = out;                           // [256][128][1024]
    float* hT = out + (size_t)TB * H_;         // [128][1024]
    float* cT = hT + BH;                       // [128][1024]

    cvt_kernel<<<2048, 256, 0, stream>>>(x,   xb,   TB * I_);
    cvt_kernel<<<512,  256, 0, stream>>>(Wih, wihb, G_ * I_);
    cvt_kernel<<<512,  256, 0, stream>>>(Whh, whhb, G_ * H_);
    cvt_h0_kernel<<<128, 256, 0, stream>>>(h0, hbuf, BH);          // buf0 = h0, tag 0
    init_b1_kernel<<<64, 256, 0, stream>>>((unsigned*)(hbuf + BH)); // buf1 = tag-1 filler
    bias_kernel<<<16, 256, 0, stream>>>(bih, bhh, bias);

    pregemm<<<8192, 256, 0, stream>>>(xb, wihb, bias, gx);

    lstm_recur<<<256, 512, 0, stream>>>(whhb, gx, c0, hbuf, ys, hT, cT);
}